// Round 15
// baseline (304.413 us; speedup 1.0000x reference)
//
#include <hip/hip_runtime.h>
#include <hip/hip_bf16.h>

typedef __attribute__((ext_vector_type(8))) short bf16x8;
typedef __attribute__((ext_vector_type(4))) float f32x4;
typedef __attribute__((ext_vector_type(4))) int i32x4;
typedef __attribute__((ext_vector_type(2))) unsigned int u32x2;
typedef __attribute__((ext_vector_type(4))) unsigned int u32x4;

// RNE fp32 -> bf16 bits (inputs finite; no NaN handling needed)
__device__ __forceinline__ unsigned int f2bf(float f) {
    union { float f; unsigned int u; } v; v.f = f;
    unsigned int u = v.u;
    u += 0x7FFFu + ((u >> 16) & 1u);
    return u >> 16;
}

__device__ __forceinline__ void gl_lds16(const void* gptr, void* lptr) {
    __builtin_amdgcn_global_load_lds(
        (const __attribute__((address_space(1))) unsigned int*)gptr,
        (__attribute__((address_space(3))) unsigned int*)lptr, 16, 0, 0);
}

// ---------- fused pre-pass convert: x (fp32->bf16) and W (int32->bf16) ----------
__global__ __launch_bounds__(256) void convert_xw_kernel(
    const float* __restrict__ x, const int* __restrict__ w,
    unsigned short* __restrict__ xb, unsigned short* __restrict__ wb,
    long long nx8, long long ntot8)
{
    long long i = (long long)blockIdx.x * blockDim.x + threadIdx.x;
    const long long stride = (long long)gridDim.x * blockDim.x;
    for (; i < ntot8; i += stride) {
        if (i < nx8) {
            const f32x4* p = (const f32x4*)(x + i * 8);
            f32x4 v0 = p[0], v1 = p[1];
            u32x4 q;
            q[0] = f2bf(v0[0]) | (f2bf(v0[1]) << 16);
            q[1] = f2bf(v0[2]) | (f2bf(v0[3]) << 16);
            q[2] = f2bf(v1[0]) | (f2bf(v1[1]) << 16);
            q[3] = f2bf(v1[2]) | (f2bf(v1[3]) << 16);
            *(u32x4*)(xb + i * 8) = q;
        } else {
            const long long j = i - nx8;
            const i32x4* p = (const i32x4*)(w + j * 8);
            i32x4 v0 = p[0], v1 = p[1];
            u32x4 q;   // int8 values are exact in bf16
            q[0] = f2bf((float)v0[0]) | (f2bf((float)v0[1]) << 16);
            q[1] = f2bf((float)v0[2]) | (f2bf((float)v0[3]) << 16);
            q[2] = f2bf((float)v1[0]) | (f2bf((float)v1[1]) << 16);
            q[3] = f2bf((float)v1[2]) | (f2bf((float)v1[3]) << 16);
            *(u32x4*)(wb + j * 8) = q;
        }
    }
}

// ---------- 256x256 GEMM, 4 waves x (128x128 per wave) -- LDS-read-BW play ----------
// Diagnosis (r14): at ds_read_b128 ~12cy (m134), r9's 8-wave config spends
// ~2300 cy/tile/CU on LDS reads vs 2483 cy MFMA -> the pipes sum, not overlap.
// Fix the RATIO: per-wave 128x128 out = 8x8 frags -> 64 MFMA per 16 reads
// (4.0 MFMA/read vs 2.67) -> LDS reads/tile/CU drop to 4x32x12 ~= 1550 cy,
// below the MFMA floor. 256 thr = 4 waves in 2x2. acc[8][8] f32x4 = 256 VGPR
// + ~100 operand VGPRs (legal: unified 512 file; 1 wave/SIMD).
// LDS 160KB: A tribuf 3x32KB @ {0,32768,65536}; B dbuf 2x32KB @ {98304,131072}.
// r9-invariant hazards, phases read {4,12,4,12}:
//  p0: read bQ(kk0,fn4-7);        MFMA aC x bP (kk0 fn0-3); stage B0(t+1)
//  p1: read aN(kk1)+bP(kk1,fn0-3);MFMA aC x bQ (kk0 fn4-7); stage B1(t+1)
//  p2: read bQ(kk1,fn4-7);        MFMA aN x bP (kk1 fn0-3); stage A0(t+2)
//  p3: stage A1(t+2); vmcnt(8); B3 barrier (globalize per-wave vmcnt -> tile
//      t+1 fully DMA'd); prefetch aC,bP (t+1 kk0); MFMA aN x bQ; END barrier.
// vmcnt(8) = A(t+2)'s own 8 stage-loads may stay in flight; kt+2>=NT -> vmcnt(0).
__global__ __launch_bounds__(256, 1) void gemm256_kernel(
    const unsigned short* __restrict__ A, const unsigned short* __restrict__ Bw,
    const float* __restrict__ wscale, const float* __restrict__ bias,
    float* __restrict__ out, int M, int N, int K)
{
    __shared__ unsigned char lds[163840];
    const int B0OFF = 98304;

    const int tid  = threadIdx.x;
    const int lane = tid & 63;
    const int wid  = tid >> 6;
    const int wr   = wid >> 1;   // 0..1 -> 128 output rows each
    const int wc   = wid & 1;    // 0..1 -> 128 output cols each

    const int ntn = N >> 8;
    const int nwg = gridDim.x;
    int bid = blockIdx.x;
    if ((nwg & 7) == 0) {                       // XCD-aware chunked swizzle (T1)
        const int cpx = nwg >> 3;
        bid = (bid & 7) * cpx + (bid >> 3);
    }
    const int bm = bid / ntn;
    const int bn = bid % ntn;
    const int NT = K >> 6;

    const char* Abase = (const char*)(A  + (size_t)bm * 256 * K);
    const char* Bbase = (const char*)(Bw + (size_t)bn * 256 * K);
    const size_t rowb = (size_t)K * 2;

    // staging: half-tile = 128 rows x 128B (16KB); 256 thr -> 4 gl_lds each.
    // Linear LDS dest; source column pre-swizzled (rule 21):
    // LDS(row, s) = global(row, s ^ (row&7)), 16B slots; row&7 == (tid>>3)&7.
    const int s_colb = (((tid & 7) ^ ((tid >> 3) & 7)) << 4);
    const int s_rsub = tid >> 3;                 // 0..31 within each pass
    const int s_ldso = tid * 16;

    auto stageHalf = [&](const char* gRowBase, char* lhalf) {
#pragma unroll
        for (int p = 0; p < 4; ++p)
            gl_lds16(gRowBase + (size_t)(p * 32 + s_rsub) * rowb + s_colb,
                     lhalf + p * 4096 + s_ldso);
    };
    auto Ag = [&](int kt, int h) { return Abase + (size_t)kt * 128 + (size_t)(h * 128) * rowb; };
    auto Bg = [&](int kt, int h) { return Bbase + (size_t)kt * 128 + (size_t)(h * 128) * rowb; };

    // fragment-read addressing (swizzled; same family as r9 -> 0 conflicts)
    const int arow = (wr * 128 + (lane & 15)) * 128;
    const int brow = (wc * 128 + (lane & 15)) * 128;
    const int csw0 = (((lane >> 4) * 16))      ^ ((lane & 7) << 4);
    const int csw1 = (((lane >> 4) * 16) + 64) ^ ((lane & 7) << 4);

    f32x4 acc[8][8];
#pragma unroll
    for (int mi = 0; mi < 8; ++mi)
#pragma unroll
        for (int ni = 0; ni < 8; ++ni)
            acc[mi][ni] = (f32x4){0.f, 0.f, 0.f, 0.f};

    bf16x8 aC[8], aN[8], bP[4], bQ[4];

    // ---- prologue: A(0)->Atri0, B(0)->Bbuf0, A(1)->Atri1; vmcnt(8) ----
    stageHalf(Ag(0, 0), (char*)lds + 0);
    stageHalf(Ag(0, 1), (char*)lds + 16384);
    stageHalf(Bg(0, 0), (char*)lds + B0OFF);
    stageHalf(Bg(0, 1), (char*)lds + B0OFF + 16384);
    if (NT > 1) {
        stageHalf(Ag(1, 0), (char*)lds + 32768);
        stageHalf(Ag(1, 1), (char*)lds + 32768 + 16384);
        asm volatile("s_waitcnt vmcnt(8)" ::: "memory");   // A(1) may stay in flight
    } else {
        asm volatile("s_waitcnt vmcnt(0)" ::: "memory");
    }
    __builtin_amdgcn_sched_barrier(0);
    asm volatile("s_barrier" ::: "memory");
    // preload tile 0: aC (kk0, 8 frags) + bP (kk0, fn0-3)
    {
        const char* Al = (const char*)lds;
        const char* Bl = (const char*)lds + B0OFF;
#pragma unroll
        for (int fm = 0; fm < 8; ++fm) aC[fm] = *(const bf16x8*)(Al + arow + fm * 2048 + csw0);
#pragma unroll
        for (int fn = 0; fn < 4; ++fn) bP[fn] = *(const bf16x8*)(Bl + brow + fn * 2048 + csw0);
    }

    int acur = 0, anxt = 32768, ann = 65536;   // A tribuf rotation
    int bcur = B0OFF, both = B0OFF + 32768;    // B dbuf

    for (int kt = 0; kt < NT; ++kt) {
        const char* Al = (const char*)lds + acur;
        const char* Bl = (const char*)lds + bcur;
        char* Bs  = (char*)lds + both;          // B(t+1) dest (other B buf)
        char* As2 = (char*)lds + ann;           // A(t+2) dest (A(t-1)'s buf)

        // ---- p0: read bQ (kk0 fn4-7); stage B0(t+1); MFMA aC x bP ----
        if (kt + 1 < NT) stageHalf(Bg(kt + 1, 0), Bs);
#pragma unroll
        for (int fn = 0; fn < 4; ++fn) bQ[fn] = *(const bf16x8*)(Bl + brow + (fn + 4) * 2048 + csw0);
        __builtin_amdgcn_s_setprio(1);
#pragma unroll
        for (int fm = 0; fm < 8; ++fm)
#pragma unroll
            for (int fn = 0; fn < 4; ++fn)
                acc[fm][fn] = __builtin_amdgcn_mfma_f32_16x16x32_bf16(aC[fm], bP[fn], acc[fm][fn], 0, 0, 0);
        __builtin_amdgcn_s_setprio(0);

        // ---- p1: read aN (kk1) + bP (kk1 fn0-3); stage B1(t+1); MFMA aC x bQ ----
        if (kt + 1 < NT) stageHalf(Bg(kt + 1, 1), Bs + 16384);
#pragma unroll
        for (int fm = 0; fm < 8; ++fm) aN[fm] = *(const bf16x8*)(Al + arow + fm * 2048 + csw1);
#pragma unroll
        for (int fn = 0; fn < 4; ++fn) bP[fn] = *(const bf16x8*)(Bl + brow + fn * 2048 + csw1);
        __builtin_amdgcn_s_setprio(1);
#pragma unroll
        for (int fm = 0; fm < 8; ++fm)
#pragma unroll
            for (int fn = 0; fn < 4; ++fn)
                acc[fm][fn + 4] = __builtin_amdgcn_mfma_f32_16x16x32_bf16(aC[fm], bQ[fn], acc[fm][fn + 4], 0, 0, 0);
        __builtin_amdgcn_s_setprio(0);

        // ---- p2: read bQ (kk1 fn4-7); stage A0(t+2); MFMA aN x bP ----
        if (kt + 2 < NT) stageHalf(Ag(kt + 2, 0), As2);
#pragma unroll
        for (int fn = 0; fn < 4; ++fn) bQ[fn] = *(const bf16x8*)(Bl + brow + (fn + 4) * 2048 + csw1);
        __builtin_amdgcn_s_setprio(1);
#pragma unroll
        for (int fm = 0; fm < 8; ++fm)
#pragma unroll
            for (int fn = 0; fn < 4; ++fn)
                acc[fm][fn] = __builtin_amdgcn_mfma_f32_16x16x32_bf16(aN[fm], bP[fn], acc[fm][fn], 0, 0, 0);
        __builtin_amdgcn_s_setprio(0);

        // ---- p3: stage A1(t+2); vmcnt(8); B3; prefetch aC,bP(t+1); MFMA aN x bQ; END ----
        if (kt + 2 < NT) stageHalf(Ag(kt + 2, 1), As2 + 16384);
        if (kt + 1 < NT) {
            if (kt + 2 < NT) { asm volatile("s_waitcnt vmcnt(8)" ::: "memory"); }
            else             { asm volatile("s_waitcnt vmcnt(0)" ::: "memory"); }
            __builtin_amdgcn_sched_barrier(0);
            asm volatile("s_barrier" ::: "memory");          // B3: globalize vmcnt ->
                                                             // tile t+1 fully landed
            const char* nAl = (const char*)lds + anxt;
            const char* nBl = (const char*)lds + both;
#pragma unroll
            for (int fm = 0; fm < 8; ++fm) aC[fm] = *(const bf16x8*)(nAl + arow + fm * 2048 + csw0);
#pragma unroll
            for (int fn = 0; fn < 4; ++fn) bP[fn] = *(const bf16x8*)(nBl + brow + fn * 2048 + csw0);
        }
        __builtin_amdgcn_s_setprio(1);
#pragma unroll
        for (int fm = 0; fm < 8; ++fm)
#pragma unroll
            for (int fn = 0; fn < 4; ++fn)
                acc[fm][fn + 4] = __builtin_amdgcn_mfma_f32_16x16x32_bf16(aN[fm], bQ[fn], acc[fm][fn + 4], 0, 0, 0);
        __builtin_amdgcn_s_setprio(0);
        asm volatile("s_barrier" ::: "memory");              // END: region handoff + swap

        const int at = acur; acur = anxt; anxt = ann; ann = at;
        const int bt = bcur; bcur = both; both = bt;
    }

    // epilogue: out = acc*scale + bias ; C/D layout col=lane&15, row=(lane>>4)*4+i
    const float scale = *wscale;
    const int orow0 = bm * 256 + wr * 128 + ((lane >> 4) << 2);
    const int ocol0 = bn * 256 + wc * 128 + (lane & 15);
#pragma unroll
    for (int fn = 0; fn < 8; ++fn) {
        const int col = ocol0 + 16 * fn;
        const float bb = bias[col];
#pragma unroll
        for (int fm = 0; fm < 8; ++fm) {
            const int row0 = orow0 + 16 * fm;
#pragma unroll
            for (int i = 0; i < 4; ++i)
                out[(size_t)(row0 + i) * N + col] = acc[fm][fn][i] * scale + bb;
        }
    }
}

// ---------- fallback: round-2 fused kernel (passes; used only if ws too small) ----------
__device__ __forceinline__ int swz(int row, int byte_in_row) {
    return row * 128 + (byte_in_row ^ ((row & 7) << 4));
}

__global__ __launch_bounds__(256) void qlinear_fused_kernel(
    const float* __restrict__ X, const int* __restrict__ W,
    const float* __restrict__ wscale, const float* __restrict__ bias,
    float* __restrict__ out, int M, int N, int K)
{
    __shared__ unsigned char smem[32768];

    const int t    = threadIdx.x;
    const int lane = t & 63;
    const int wid  = t >> 6;
    const int wr   = wid >> 1;
    const int wc   = wid & 1;

    const int ntn = N >> 7;
    const int bm  = blockIdx.x / ntn;
    const int bn  = blockIdx.x % ntn;
    const int NT  = K >> 6;

    const float* Ab = X + (size_t)bm * 128 * K;
    const int*   Bb = W + (size_t)bn * 128 * K;

    const int srow = t >> 4, sc4 = t & 15;

    f32x4 av[8];
    i32x4 bv[8];

    auto loadAB = [&](int kt) {
        const float* Ap = Ab + kt * 64 + sc4 * 4;
#pragma unroll
        for (int l = 0; l < 8; ++l)
            av[l] = *(const f32x4*)(Ap + (size_t)(srow + 16 * l) * K);
        const int* Bp = Bb + kt * 64 + sc4 * 4;
#pragma unroll
        for (int l = 0; l < 8; ++l)
            bv[l] = *(const i32x4*)(Bp + (size_t)(srow + 16 * l) * K);
    };

    auto writeAB = [&]() {
#pragma unroll
        for (int l = 0; l < 8; ++l) {
            const int row = srow + 16 * l;
            u32x2 pk;
            pk[0] = f2bf(av[l][0]) | (f2bf(av[l][1]) << 16);
            pk[1] = f2bf(av[l][2]) | (f2bf(av[l][3]) << 16);
            *(u32x2*)(smem + swz(row, sc4 * 8)) = pk;
        }
#pragma unroll
        for (int l = 0; l < 8; ++l) {
            const int row = srow + 16 * l;
            u32x2 pk;
            pk[0] = f2bf((float)bv[l][0]) | (f2bf((float)bv[l][1]) << 16);
            pk[1] = f2bf((float)bv[l][2]) | (f2bf((float)bv[l][3]) << 16);
            *(u32x2*)(smem + 16384 + swz(row, sc4 * 8)) = pk;
        }
    };

    f32x4 acc[4][4];
#pragma unroll
    for (int mi = 0; mi < 4; ++mi)
#pragma unroll
        for (int ni = 0; ni < 4; ++ni)
            acc[mi][ni] = (f32x4){0.f, 0.f, 0.f, 0.f};

    const int kbyte = (lane >> 4) * 16;
    const int afr   = wr * 64 + (lane & 15);
    const int bfr   = wc * 64 + (lane & 15);

    loadAB(0);

    for (int kt = 0; kt < NT; ++kt) {
        writeAB();
        __syncthreads();
        if (kt + 1 < NT) loadAB(kt + 1);
#pragma unroll
        for (int kk = 0; kk < 2; ++kk) {
            bf16x8 a[4], b[4];
#pragma unroll
            for (int mi = 0; mi < 4; ++mi)
                a[mi] = *(const bf16x8*)(smem + swz(afr + 16 * mi, kk * 64 + kbyte));
#pragma unroll
            for (int ni = 0; ni < 4; ++ni)
                b[ni] = *(const bf16x8*)(smem + 16384 + swz(bfr + 16 * ni, kk * 64 + kbyte));
#pragma unroll
            for (int mi = 0; mi < 4; ++mi)
#pragma unroll
                for (int ni = 0; ni < 4; ++ni)
                    acc[mi][ni] = __builtin_amdgcn_mfma_f32_16x16x32_bf16(
                        a[mi], b[ni], acc[mi][ni], 0, 0, 0);
        }
        __syncthreads();
    }

    const float scale = *wscale;
    const int orow0 = bm * 128 + wr * 64 + ((lane >> 4) << 2);
    const int ocol0 = bn * 128 + wc * 64 + (lane & 15);
#pragma unroll
    for (int ni = 0; ni < 4; ++ni) {
        const int col = ocol0 + 16 * ni;
        const float bb = bias[col];
#pragma unroll
        for (int mi = 0; mi < 4; ++mi) {
            const int row0 = orow0 + 16 * mi;
#pragma unroll
            for (int i = 0; i < 4; ++i)
                out[(size_t)(row0 + i) * N + col] = acc[mi][ni][i] * scale + bb;
        }
    }
}

extern "C" void kernel_launch(void* const* d_in, const int* in_sizes, int n_in,
                              void* d_out, int out_size, void* d_ws, size_t ws_size,
                              hipStream_t stream) {
    const float* x      = (const float*)d_in[0];
    const int*   w      = (const int*)d_in[1];      // int inputs arrive as int32
    const float* wscale = (const float*)d_in[2];
    const float* bias   = (const float*)d_in[3];
    float*       out    = (float*)d_out;

    const int DOUT = in_sizes[3];
    const int DIN  = in_sizes[1] / DOUT;
    const int M    = in_sizes[0] / DIN;

    const size_t xb_bytes = (size_t)M * DIN * 2;
    const size_t wb_bytes = (size_t)DOUT * DIN * 2;

    if (ws_size >= xb_bytes + wb_bytes && (M % 256) == 0 && (DOUT % 256) == 0
        && (DIN % 64) == 0 && (DIN / 64) >= 2) {
        unsigned short* xb = (unsigned short*)d_ws;
        unsigned short* wb = (unsigned short*)((char*)d_ws + xb_bytes);

        const long long nx8 = (long long)M * DIN / 8;
        const long long nw8 = (long long)DOUT * DIN / 8;
        convert_xw_kernel<<<2048, 256, 0, stream>>>(x, w, xb, wb, nx8, nx8 + nw8);

        dim3 grid((M / 256) * (DOUT / 256));
        gemm256_kernel<<<grid, 256, 0, stream>>>(xb, wb, wscale, bias, out, M, DOUT, DIN);
    } else {
        dim3 grid((M / 128) * (DOUT / 128));
        qlinear_fused_kernel<<<grid, 256, 0, stream>>>(x, w, wscale, bias, out, M, DOUT, DIN);
    }
}

// Round 16
// 278.747 us; speedup vs baseline: 1.0921x; 1.0921x over previous
//
#include <hip/hip_runtime.h>
#include <hip/hip_bf16.h>

typedef __attribute__((ext_vector_type(8))) short bf16x8;
typedef __attribute__((ext_vector_type(4))) float f32x4;
typedef __attribute__((ext_vector_type(4))) int i32x4;
typedef __attribute__((ext_vector_type(2))) unsigned int u32x2;
typedef __attribute__((ext_vector_type(4))) unsigned int u32x4;

// RNE fp32 -> bf16 bits (inputs finite; no NaN handling needed)
__device__ __forceinline__ unsigned int f2bf(float f) {
    union { float f; unsigned int u; } v; v.f = f;
    unsigned int u = v.u;
    u += 0x7FFFu + ((u >> 16) & 1u);
    return u >> 16;
}

__device__ __forceinline__ void gl_lds16(const void* gptr, void* lptr) {
    __builtin_amdgcn_global_load_lds(
        (const __attribute__((address_space(1))) unsigned int*)gptr,
        (__attribute__((address_space(3))) unsigned int*)lptr, 16, 0, 0);
}

// ---------- fused pre-pass convert: x (fp32->bf16) and W (int32->bf16) ----------
__global__ __launch_bounds__(256) void convert_xw_kernel(
    const float* __restrict__ x, const int* __restrict__ w,
    unsigned short* __restrict__ xb, unsigned short* __restrict__ wb,
    long long nx8, long long ntot8)
{
    long long i = (long long)blockIdx.x * blockDim.x + threadIdx.x;
    const long long stride = (long long)gridDim.x * blockDim.x;
    for (; i < ntot8; i += stride) {
        if (i < nx8) {
            const f32x4* p = (const f32x4*)(x + i * 8);
            f32x4 v0 = p[0], v1 = p[1];
            u32x4 q;
            q[0] = f2bf(v0[0]) | (f2bf(v0[1]) << 16);
            q[1] = f2bf(v0[2]) | (f2bf(v0[3]) << 16);
            q[2] = f2bf(v1[0]) | (f2bf(v1[1]) << 16);
            q[3] = f2bf(v1[2]) | (f2bf(v1[3]) << 16);
            *(u32x4*)(xb + i * 8) = q;
        } else {
            const long long j = i - nx8;
            const i32x4* p = (const i32x4*)(w + j * 8);
            i32x4 v0 = p[0], v1 = p[1];
            u32x4 q;   // int8 values are exact in bf16
            q[0] = f2bf((float)v0[0]) | (f2bf((float)v0[1]) << 16);
            q[1] = f2bf((float)v0[2]) | (f2bf((float)v0[3]) << 16);
            q[2] = f2bf((float)v1[0]) | (f2bf((float)v1[1]) << 16);
            q[3] = f2bf((float)v1[2]) | (f2bf((float)v1[3]) << 16);
            *(u32x4*)(wb + j * 8) = q;
        }
    }
}

// ---------- 256x256 pipelined GEMM, A tribuf / B dbuf (SESSION OPTIMUM, r9/r14) ----------
// Verified best: total 278.3 us, GEMM 241.6 us (~1023 TF), MfmaUtil 51.2%,
// 0 bank conflicts, absmax 1.0. 512 thr = 8 waves in 4Mx2N; per-wave 64x128.
// LDS 160KB: A tribuf 3x32KB @ {0,32768,65536}; B dbuf 2x32KB @ {98304,131072}.
// Phase p issues phase p+1's ds_reads; MFMAs run on regs read last phase.
// Stage rotation during tile t: p0/p1 -> B(t+1) halves; p2/p3 -> A(t+2) halves
// (into A(t-1)'s buffer, freed via END(t-1)). 2 barriers/tile:
//   B3  (p3, after vmcnt(4)): globalizes per-wave vmcnt -> tile t+1 fully
//       DMA-complete across ALL waves before any prefetch-read of it (r6 race).
//   END (end p3): all tile-t reads operand-waited -> next tile may DMA.
// Session ledger (8 structural variants, all falsified vs this config):
//   r5 8-phase lockstep 45% | r7 3-barrier 49% | r8 B-tribuf depth null |
//   r10 2-block TLP -15% | r11 32x32 MFMA 4-way LDS conflict -11% |
//   r12 per-phase interleave -10% | r13 supertile L2 (FETCH -35%, dur +4%) |
//   r15 128x128/wave (VGPR cap 256, occ 11%, MfmaUtil 42.5%).
// Plateau mechanism: 8 waves/CU interleave ~50% MFMA + ~45% LDS-read on the
// same SIMDs; fewer waves lose latency hiding, more LDS work loses ratio.
__global__ __launch_bounds__(512, 2) void gemm256_kernel(
    const unsigned short* __restrict__ A, const unsigned short* __restrict__ Bw,
    const float* __restrict__ wscale, const float* __restrict__ bias,
    float* __restrict__ out, int M, int N, int K)
{
    __shared__ unsigned char lds[163840];
    const int B0OFF = 98304;

    const int tid  = threadIdx.x;
    const int lane = tid & 63;
    const int wid  = tid >> 6;
    const int wr   = wid >> 1;   // 0..3 -> 64 output rows each
    const int wc   = wid & 1;    // 0..1 -> 128 output cols each

    const int ntn = N >> 8;
    const int nwg = gridDim.x;
    int bid = blockIdx.x;
    if ((nwg & 7) == 0) {                       // XCD-aware chunked swizzle (T1)
        const int cpx = nwg >> 3;
        bid = (bid & 7) * cpx + (bid >> 3);
    }
    const int bm = bid / ntn;
    const int bn = bid % ntn;
    const int NT = K >> 6;

    const char* Abase = (const char*)(A  + (size_t)bm * 256 * K);
    const char* Bbase = (const char*)(Bw + (size_t)bn * 256 * K);
    const size_t rowb = (size_t)K * 2;

    // staging: half-tile = 128 rows x 128B (16KB); 2 gl_lds per thread.
    // Linear LDS dest; source column pre-swizzled (rule 21).
    const int s_colb = (((lane & 7) ^ (lane >> 3)) << 4);
    const int s_rsub = wid * 8 + (lane >> 3);
    const int s_ldso = wid * 1024 + lane * 16;

    auto stageHalf = [&](const char* gRowBase, char* lhalf) {
#pragma unroll
        for (int q = 0; q < 2; ++q)
            gl_lds16(gRowBase + (size_t)(q * 64 + s_rsub) * rowb + s_colb,
                     lhalf + q * 8192 + s_ldso);
    };
    auto Ag = [&](int kt, int h) { return Abase + (size_t)kt * 128 + (size_t)(h * 128) * rowb; };
    auto Bg = [&](int kt, int h) { return Bbase + (size_t)kt * 128 + (size_t)(h * 128) * rowb; };

    // fragment-read addressing (swizzled)
    const int arow = (wr * 64  + (lane & 15)) * 128;
    const int brow = (wc * 128 + (lane & 15)) * 128;
    const int csw0 = (((lane >> 4) * 16))      ^ ((lane & 7) << 4);
    const int csw1 = (((lane >> 4) * 16) + 64) ^ ((lane & 7) << 4);

    f32x4 acc[4][8];
#pragma unroll
    for (int mi = 0; mi < 4; ++mi)
#pragma unroll
        for (int ni = 0; ni < 8; ++ni)
            acc[mi][ni] = (f32x4){0.f, 0.f, 0.f, 0.f};

    bf16x8 a0[4], a1[4], bA[4], bB[4];

    // ---- prologue: A(0)->Abuf0, B(0)->Bbuf0, A(1)->Abuf1; tile0 must land ----
    stageHalf(Ag(0, 0), (char*)lds + 0);
    stageHalf(Ag(0, 1), (char*)lds + 16384);
    stageHalf(Bg(0, 0), (char*)lds + B0OFF);
    stageHalf(Bg(0, 1), (char*)lds + B0OFF + 16384);
    if (NT > 1) {
        stageHalf(Ag(1, 0), (char*)lds + 32768);
        stageHalf(Ag(1, 1), (char*)lds + 32768 + 16384);
        asm volatile("s_waitcnt vmcnt(4)" ::: "memory");   // A(1) may stay in flight
    } else {
        asm volatile("s_waitcnt vmcnt(0)" ::: "memory");
    }
    __builtin_amdgcn_sched_barrier(0);
    asm volatile("s_barrier" ::: "memory");
    // R0 of tile 0: a0 (kk0) + bA (fn0-3, kk0)
    {
        const char* Al = (const char*)lds;
        const char* Bl = (const char*)lds + B0OFF;
#pragma unroll
        for (int fm = 0; fm < 4; ++fm) a0[fm] = *(const bf16x8*)(Al + arow + fm * 2048 + csw0);
#pragma unroll
        for (int fn = 0; fn < 4; ++fn) bA[fn] = *(const bf16x8*)(Bl + brow + fn * 2048 + csw0);
    }

    int acur = 0, anxt = 32768, ann = 65536;   // A tribuf rotation
    int bcur = B0OFF, both = B0OFF + 32768;    // B dbuf

    for (int kt = 0; kt < NT; ++kt) {
        const char* Al = (const char*)lds + acur;
        const char* Bl = (const char*)lds + bcur;
        char* Bs  = (char*)lds + both;          // B(t+1) dest (other B buf)
        char* As2 = (char*)lds + ann;           // A(t+2) dest (A(t-1)'s buf)

        // ---- p0: stage B0(t+1); read R1 {a1 kk1, bB fn4-7 kk0}; MFMA a0 x bA ----
        if (kt + 1 < NT) stageHalf(Bg(kt + 1, 0), Bs);
#pragma unroll
        for (int fm = 0; fm < 4; ++fm) a1[fm] = *(const bf16x8*)(Al + arow + fm * 2048 + csw1);
#pragma unroll
        for (int fn = 0; fn < 4; ++fn) bB[fn] = *(const bf16x8*)(Bl + brow + (fn + 4) * 2048 + csw0);
        __builtin_amdgcn_s_setprio(1);
#pragma unroll
        for (int fm = 0; fm < 4; ++fm)
#pragma unroll
            for (int fn = 0; fn < 4; ++fn)
                acc[fm][fn] = __builtin_amdgcn_mfma_f32_16x16x32_bf16(a0[fm], bA[fn], acc[fm][fn], 0, 0, 0);
        __builtin_amdgcn_s_setprio(0);

        // ---- p1: stage B1(t+1); read R2 {bA <- fn0-3 kk1}; MFMA a0 x bB ----
        if (kt + 1 < NT) stageHalf(Bg(kt + 1, 1), Bs + 16384);
#pragma unroll
        for (int fn = 0; fn < 4; ++fn) bA[fn] = *(const bf16x8*)(Bl + brow + fn * 2048 + csw1);
        __builtin_amdgcn_s_setprio(1);
#pragma unroll
        for (int fm = 0; fm < 4; ++fm)
#pragma unroll
            for (int fn = 0; fn < 4; ++fn)
                acc[fm][fn + 4] = __builtin_amdgcn_mfma_f32_16x16x32_bf16(a0[fm], bB[fn], acc[fm][fn + 4], 0, 0, 0);
        __builtin_amdgcn_s_setprio(0);
        // (no MID barrier: A(t+2) goes to A(t-1)'s buffer, freed via END(t-1))

        // ---- p2: stage A0(t+2); read R3 {bB <- fn4-7 kk1}; MFMA a1 x bA ----
        if (kt + 2 < NT) stageHalf(Ag(kt + 2, 0), As2);
#pragma unroll
        for (int fn = 0; fn < 4; ++fn) bB[fn] = *(const bf16x8*)(Bl + brow + (fn + 4) * 2048 + csw1);
        __builtin_amdgcn_s_setprio(1);
#pragma unroll
        for (int fm = 0; fm < 4; ++fm)
#pragma unroll
            for (int fn = 0; fn < 4; ++fn)
                acc[fm][fn] = __builtin_amdgcn_mfma_f32_16x16x32_bf16(a1[fm], bA[fn], acc[fm][fn], 0, 0, 0);
        __builtin_amdgcn_s_setprio(0);

        // ---- p3: stage A1(t+2); vmcnt(4); B3; read R0'(t+1); MFMA a1 x bB; END ----
        if (kt + 2 < NT) stageHalf(Ag(kt + 2, 1), As2 + 16384);
        if (kt + 1 < NT) {
            if (kt + 2 < NT) { asm volatile("s_waitcnt vmcnt(4)" ::: "memory"); }
            else             { asm volatile("s_waitcnt vmcnt(0)" ::: "memory"); }
            __builtin_amdgcn_sched_barrier(0);
            asm volatile("s_barrier" ::: "memory");          // B3: globalize vmcnt ->
                                                             // tile t+1 fully landed
            const char* nAl = (const char*)lds + anxt;
            const char* nBl = (const char*)lds + both;
#pragma unroll
            for (int fm = 0; fm < 4; ++fm) a0[fm] = *(const bf16x8*)(nAl + arow + fm * 2048 + csw0);
#pragma unroll
            for (int fn = 0; fn < 4; ++fn) bA[fn] = *(const bf16x8*)(nBl + brow + fn * 2048 + csw0);
        }
        __builtin_amdgcn_s_setprio(1);
#pragma unroll
        for (int fm = 0; fm < 4; ++fm)
#pragma unroll
            for (int fn = 0; fn < 4; ++fn)
                acc[fm][fn + 4] = __builtin_amdgcn_mfma_f32_16x16x32_bf16(a1[fm], bB[fn], acc[fm][fn + 4], 0, 0, 0);
        __builtin_amdgcn_s_setprio(0);
        asm volatile("s_barrier" ::: "memory");              // END: region handoff + swap

        const int at = acur; acur = anxt; anxt = ann; ann = at;
        const int bt = bcur; bcur = both; both = bt;
    }

    // epilogue: out = acc*scale + bias ; C/D layout col=lane&15, row=(lane>>4)*4+i
    const float scale = *wscale;
    const int orow0 = bm * 256 + wr * 64  + ((lane >> 4) << 2);
    const int ocol0 = bn * 256 + wc * 128 + (lane & 15);
#pragma unroll
    for (int fn = 0; fn < 8; ++fn) {
        const int col = ocol0 + 16 * fn;
        const float bb = bias[col];
#pragma unroll
        for (int fm = 0; fm < 4; ++fm) {
            const int row0 = orow0 + 16 * fm;
#pragma unroll
            for (int i = 0; i < 4; ++i)
                out[(size_t)(row0 + i) * N + col] = acc[fm][fn][i] * scale + bb;
        }
    }
}

// ---------- fallback: round-2 fused kernel (passes; used only if ws too small) ----------
__device__ __forceinline__ int swz(int row, int byte_in_row) {
    return row * 128 + (byte_in_row ^ ((row & 7) << 4));
}

__global__ __launch_bounds__(256) void qlinear_fused_kernel(
    const float* __restrict__ X, const int* __restrict__ W,
    const float* __restrict__ wscale, const float* __restrict__ bias,
    float* __restrict__ out, int M, int N, int K)
{
    __shared__ unsigned char smem[32768];

    const int t    = threadIdx.x;
    const int lane = t & 63;
    const int wid  = t >> 6;
    const int wr   = wid >> 1;
    const int wc   = wid & 1;

    const int ntn = N >> 7;
    const int bm  = blockIdx.x / ntn;
    const int bn  = blockIdx.x % ntn;
    const int NT  = K >> 6;

    const float* Ab = X + (size_t)bm * 128 * K;
    const int*   Bb = W + (size_t)bn * 128 * K;

    const int srow = t >> 4, sc4 = t & 15;

    f32x4 av[8];
    i32x4 bv[8];

    auto loadAB = [&](int kt) {
        const float* Ap = Ab + kt * 64 + sc4 * 4;
#pragma unroll
        for (int l = 0; l < 8; ++l)
            av[l] = *(const f32x4*)(Ap + (size_t)(srow + 16 * l) * K);
        const int* Bp = Bb + kt * 64 + sc4 * 4;
#pragma unroll
        for (int l = 0; l < 8; ++l)
            bv[l] = *(const i32x4*)(Bp + (size_t)(srow + 16 * l) * K);
    };

    auto writeAB = [&]() {
#pragma unroll
        for (int l = 0; l < 8; ++l) {
            const int row = srow + 16 * l;
            u32x2 pk;
            pk[0] = f2bf(av[l][0]) | (f2bf(av[l][1]) << 16);
            pk[1] = f2bf(av[l][2]) | (f2bf(av[l][3]) << 16);
            *(u32x2*)(smem + swz(row, sc4 * 8)) = pk;
        }
#pragma unroll
        for (int l = 0; l < 8; ++l) {
            const int row = srow + 16 * l;
            u32x2 pk;
            pk[0] = f2bf((float)bv[l][0]) | (f2bf((float)bv[l][1]) << 16);
            pk[1] = f2bf((float)bv[l][2]) | (f2bf((float)bv[l][3]) << 16);
            *(u32x2*)(smem + 16384 + swz(row, sc4 * 8)) = pk;
        }
    };

    f32x4 acc[4][4];
#pragma unroll
    for (int mi = 0; mi < 4; ++mi)
#pragma unroll
        for (int ni = 0; ni < 4; ++ni)
            acc[mi][ni] = (f32x4){0.f, 0.f, 0.f, 0.f};

    const int kbyte = (lane >> 4) * 16;
    const int afr   = wr * 64 + (lane & 15);
    const int bfr   = wc * 64 + (lane & 15);

    loadAB(0);

    for (int kt = 0; kt < NT; ++kt) {
        writeAB();
        __syncthreads();
        if (kt + 1 < NT) loadAB(kt + 1);
#pragma unroll
        for (int kk = 0; kk < 2; ++kk) {
            bf16x8 a[4], b[4];
#pragma unroll
            for (int mi = 0; mi < 4; ++mi)
                a[mi] = *(const bf16x8*)(smem + swz(afr + 16 * mi, kk * 64 + kbyte));
#pragma unroll
            for (int ni = 0; ni < 4; ++ni)
                b[ni] = *(const bf16x8*)(smem + 16384 + swz(bfr + 16 * ni, kk * 64 + kbyte));
#pragma unroll
            for (int mi = 0; mi < 4; ++mi)
#pragma unroll
                for (int ni = 0; ni < 4; ++ni)
                    acc[mi][ni] = __builtin_amdgcn_mfma_f32_16x16x32_bf16(
                        a[mi], b[ni], acc[mi][ni], 0, 0, 0);
        }
        __syncthreads();
    }

    const float scale = *wscale;
    const int orow0 = bm * 128 + wr * 64 + ((lane >> 4) << 2);
    const int ocol0 = bn * 128 + wc * 64 + (lane & 15);
#pragma unroll
    for (int ni = 0; ni < 4; ++ni) {
        const int col = ocol0 + 16 * ni;
        const float bb = bias[col];
#pragma unroll
        for (int mi = 0; mi < 4; ++mi) {
            const int row0 = orow0 + 16 * mi;
#pragma unroll
            for (int i = 0; i < 4; ++i)
                out[(size_t)(row0 + i) * N + col] = acc[mi][ni][i] * scale + bb;
        }
    }
}

extern "C" void kernel_launch(void* const* d_in, const int* in_sizes, int n_in,
                              void* d_out, int out_size, void* d_ws, size_t ws_size,
                              hipStream_t stream) {
    const float* x      = (const float*)d_in[0];
    const int*   w      = (const int*)d_in[1];      // int inputs arrive as int32
    const float* wscale = (const float*)d_in[2];
    const float* bias   = (const float*)d_in[3];
    float*       out    = (float*)d_out;

    const int DOUT = in_sizes[3];
    const int DIN  = in_sizes[1] / DOUT;
    const int M    = in_sizes[0] / DIN;

    const size_t xb_bytes = (size_t)M * DIN * 2;
    const size_t wb_bytes = (size_t)DOUT * DIN * 2;

    if (ws_size >= xb_bytes + wb_bytes && (M % 256) == 0 && (DOUT % 256) == 0
        && (DIN % 64) == 0 && (DIN / 64) >= 2) {
        unsigned short* xb = (unsigned short*)d_ws;
        unsigned short* wb = (unsigned short*)((char*)d_ws + xb_bytes);

        const long long nx8 = (long long)M * DIN / 8;
        const long long nw8 = (long long)DOUT * DIN / 8;
        convert_xw_kernel<<<2048, 256, 0, stream>>>(x, w, xb, wb, nx8, nx8 + nw8);

        dim3 grid((M / 256) * (DOUT / 256));
        gemm256_kernel<<<grid, 512, 0, stream>>>(xb, wb, wscale, bias, out, M, DOUT, DIN);
    } else {
        dim3 grid((M / 128) * (DOUT / 128));
        qlinear_fused_kernel<<<grid, 256, 0, stream>>>(x, w, wscale, bias, out, M, DOUT, DIN);
    }
}

// Round 17
// 275.977 us; speedup vs baseline: 1.1030x; 1.0100x over previous
//
#include <hip/hip_runtime.h>
#include <hip/hip_bf16.h>

typedef __attribute__((ext_vector_type(8))) short bf16x8;
typedef __attribute__((ext_vector_type(4))) float f32x4;
typedef __attribute__((ext_vector_type(4))) int i32x4;
typedef __attribute__((ext_vector_type(2))) unsigned int u32x2;
typedef __attribute__((ext_vector_type(4))) unsigned int u32x4;

// RNE fp32 -> bf16 bits (inputs finite; no NaN handling needed)
__device__ __forceinline__ unsigned int f2bf(float f) {
    union { float f; unsigned int u; } v; v.f = f;
    unsigned int u = v.u;
    u += 0x7FFFu + ((u >> 16) & 1u);
    return u >> 16;
}

__device__ __forceinline__ void gl_lds16(const void* gptr, void* lptr) {
    __builtin_amdgcn_global_load_lds(
        (const __attribute__((address_space(1))) unsigned int*)gptr,
        (__attribute__((address_space(3))) unsigned int*)lptr, 16, 0, 0);
}

// ---------- fused pre-pass convert: x (fp32->bf16) and W (int32->bf16) ----------
__global__ __launch_bounds__(256) void convert_xw_kernel(
    const float* __restrict__ x, const int* __restrict__ w,
    unsigned short* __restrict__ xb, unsigned short* __restrict__ wb,
    long long nx8, long long ntot8)
{
    long long i = (long long)blockIdx.x * blockDim.x + threadIdx.x;
    const long long stride = (long long)gridDim.x * blockDim.x;
    for (; i < ntot8; i += stride) {
        if (i < nx8) {
            const f32x4* p = (const f32x4*)(x + i * 8);
            f32x4 v0 = p[0], v1 = p[1];
            u32x4 q;
            q[0] = f2bf(v0[0]) | (f2bf(v0[1]) << 16);
            q[1] = f2bf(v0[2]) | (f2bf(v0[3]) << 16);
            q[2] = f2bf(v1[0]) | (f2bf(v1[1]) << 16);
            q[3] = f2bf(v1[2]) | (f2bf(v1[3]) << 16);
            *(u32x4*)(xb + i * 8) = q;
        } else {
            const long long j = i - nx8;
            const i32x4* p = (const i32x4*)(w + j * 8);
            i32x4 v0 = p[0], v1 = p[1];
            u32x4 q;   // int8 values are exact in bf16
            q[0] = f2bf((float)v0[0]) | (f2bf((float)v0[1]) << 16);
            q[1] = f2bf((float)v0[2]) | (f2bf((float)v0[3]) << 16);
            q[2] = f2bf((float)v1[0]) | (f2bf((float)v1[1]) << 16);
            q[3] = f2bf((float)v1[2]) | (f2bf((float)v1[3]) << 16);
            *(u32x4*)(wb + j * 8) = q;
        }
    }
}

// ---------- 256x256 pipelined GEMM, A tribuf / B dbuf (SESSION OPTIMUM) ----------
// Verified twice: total 278.3/278.7 us, GEMM ~241 us (~1025 TF, 41% dense peak),
// MfmaUtil 51-54%, 0 bank conflicts, absmax 1.0.
// 512 thr = 8 waves in 4Mx2N; per-wave 64x128. BK=64.
// LDS 160KB: A tribuf 3x32KB @ {0,32768,65536}; B dbuf 2x32KB @ {98304,131072}.
// Phase p issues phase p+1's ds_reads; MFMAs run on regs read last phase.
// Stage rotation during tile t: p0/p1 -> B(t+1) halves; p2/p3 -> A(t+2) halves
// (into A(t-1)'s buffer, freed via END(t-1)). 2 barriers/tile:
//   B3  (p3, after vmcnt(4)): globalizes per-wave vmcnt -> tile t+1 fully
//       DMA-complete across ALL waves before any prefetch-read of it (r6 race).
//   END (end p3): all tile-t reads operand-waited -> next tile may DMA.
// Session ledger (8 structural variants, all measured and falsified):
//   r5 8-phase lockstep 45% | r7 3-barrier 49% | r8 B-tribuf depth null |
//   r10 2-block TLP -15% | r11 32x32 MFMA 4-way LDS conflict -11% |
//   r12 per-phase interleave -10% | r13 supertile L2 (FETCH -35%, dur +4%) |
//   r15 128x128/wave (VGPR cap 256, occ 11%, -16%).
// Plateau mechanism: per K-tile/CU, MFMA ~2483 cy and ds_read traffic ~2300 cy
// share the SIMD issue ports; 8 waves/CU interleave these to ~51% MfmaUtil.
// Fewer/fatter waves lose registers + latency hiding; more waves lose ratio.
__global__ __launch_bounds__(512, 2) void gemm256_kernel(
    const unsigned short* __restrict__ A, const unsigned short* __restrict__ Bw,
    const float* __restrict__ wscale, const float* __restrict__ bias,
    float* __restrict__ out, int M, int N, int K)
{
    __shared__ unsigned char lds[163840];
    const int B0OFF = 98304;

    const int tid  = threadIdx.x;
    const int lane = tid & 63;
    const int wid  = tid >> 6;
    const int wr   = wid >> 1;   // 0..3 -> 64 output rows each
    const int wc   = wid & 1;    // 0..1 -> 128 output cols each

    const int ntn = N >> 8;
    const int nwg = gridDim.x;
    int bid = blockIdx.x;
    if ((nwg & 7) == 0) {                       // XCD-aware chunked swizzle (T1)
        const int cpx = nwg >> 3;
        bid = (bid & 7) * cpx + (bid >> 3);
    }
    const int bm = bid / ntn;
    const int bn = bid % ntn;
    const int NT = K >> 6;

    const char* Abase = (const char*)(A  + (size_t)bm * 256 * K);
    const char* Bbase = (const char*)(Bw + (size_t)bn * 256 * K);
    const size_t rowb = (size_t)K * 2;

    // staging: half-tile = 128 rows x 128B (16KB); 2 gl_lds per thread.
    // Linear LDS dest; source column pre-swizzled (rule 21).
    const int s_colb = (((lane & 7) ^ (lane >> 3)) << 4);
    const int s_rsub = wid * 8 + (lane >> 3);
    const int s_ldso = wid * 1024 + lane * 16;

    auto stageHalf = [&](const char* gRowBase, char* lhalf) {
#pragma unroll
        for (int q = 0; q < 2; ++q)
            gl_lds16(gRowBase + (size_t)(q * 64 + s_rsub) * rowb + s_colb,
                     lhalf + q * 8192 + s_ldso);
    };
    auto Ag = [&](int kt, int h) { return Abase + (size_t)kt * 128 + (size_t)(h * 128) * rowb; };
    auto Bg = [&](int kt, int h) { return Bbase + (size_t)kt * 128 + (size_t)(h * 128) * rowb; };

    // fragment-read addressing (swizzled)
    const int arow = (wr * 64  + (lane & 15)) * 128;
    const int brow = (wc * 128 + (lane & 15)) * 128;
    const int csw0 = (((lane >> 4) * 16))      ^ ((lane & 7) << 4);
    const int csw1 = (((lane >> 4) * 16) + 64) ^ ((lane & 7) << 4);

    f32x4 acc[4][8];
#pragma unroll
    for (int mi = 0; mi < 4; ++mi)
#pragma unroll
        for (int ni = 0; ni < 8; ++ni)
            acc[mi][ni] = (f32x4){0.f, 0.f, 0.f, 0.f};

    bf16x8 a0[4], a1[4], bA[4], bB[4];

    // ---- prologue: A(0)->Abuf0, B(0)->Bbuf0, A(1)->Abuf1; tile0 must land ----
    stageHalf(Ag(0, 0), (char*)lds + 0);
    stageHalf(Ag(0, 1), (char*)lds + 16384);
    stageHalf(Bg(0, 0), (char*)lds + B0OFF);
    stageHalf(Bg(0, 1), (char*)lds + B0OFF + 16384);
    if (NT > 1) {
        stageHalf(Ag(1, 0), (char*)lds + 32768);
        stageHalf(Ag(1, 1), (char*)lds + 32768 + 16384);
        asm volatile("s_waitcnt vmcnt(4)" ::: "memory");   // A(1) may stay in flight
    } else {
        asm volatile("s_waitcnt vmcnt(0)" ::: "memory");
    }
    __builtin_amdgcn_sched_barrier(0);
    asm volatile("s_barrier" ::: "memory");
    // R0 of tile 0: a0 (kk0) + bA (fn0-3, kk0)
    {
        const char* Al = (const char*)lds;
        const char* Bl = (const char*)lds + B0OFF;
#pragma unroll
        for (int fm = 0; fm < 4; ++fm) a0[fm] = *(const bf16x8*)(Al + arow + fm * 2048 + csw0);
#pragma unroll
        for (int fn = 0; fn < 4; ++fn) bA[fn] = *(const bf16x8*)(Bl + brow + fn * 2048 + csw0);
    }

    int acur = 0, anxt = 32768, ann = 65536;   // A tribuf rotation
    int bcur = B0OFF, both = B0OFF + 32768;    // B dbuf

    for (int kt = 0; kt < NT; ++kt) {
        const char* Al = (const char*)lds + acur;
        const char* Bl = (const char*)lds + bcur;
        char* Bs  = (char*)lds + both;          // B(t+1) dest (other B buf)
        char* As2 = (char*)lds + ann;           // A(t+2) dest (A(t-1)'s buf)

        // ---- p0: stage B0(t+1); read R1 {a1 kk1, bB fn4-7 kk0}; MFMA a0 x bA ----
        if (kt + 1 < NT) stageHalf(Bg(kt + 1, 0), Bs);
#pragma unroll
        for (int fm = 0; fm < 4; ++fm) a1[fm] = *(const bf16x8*)(Al + arow + fm * 2048 + csw1);
#pragma unroll
        for (int fn = 0; fn < 4; ++fn) bB[fn] = *(const bf16x8*)(Bl + brow + (fn + 4) * 2048 + csw0);
        __builtin_amdgcn_s_setprio(1);
#pragma unroll
        for (int fm = 0; fm < 4; ++fm)
#pragma unroll
            for (int fn = 0; fn < 4; ++fn)
                acc[fm][fn] = __builtin_amdgcn_mfma_f32_16x16x32_bf16(a0[fm], bA[fn], acc[fm][fn], 0, 0, 0);
        __builtin_amdgcn_s_setprio(0);

        // ---- p1: stage B1(t+1); read R2 {bA <- fn0-3 kk1}; MFMA a0 x bB ----
        if (kt + 1 < NT) stageHalf(Bg(kt + 1, 1), Bs + 16384);
#pragma unroll
        for (int fn = 0; fn < 4; ++fn) bA[fn] = *(const bf16x8*)(Bl + brow + fn * 2048 + csw1);
        __builtin_amdgcn_s_setprio(1);
#pragma unroll
        for (int fm = 0; fm < 4; ++fm)
#pragma unroll
            for (int fn = 0; fn < 4; ++fn)
                acc[fm][fn + 4] = __builtin_amdgcn_mfma_f32_16x16x32_bf16(a0[fm], bB[fn], acc[fm][fn + 4], 0, 0, 0);
        __builtin_amdgcn_s_setprio(0);
        // (no MID barrier: A(t+2) goes to A(t-1)'s buffer, freed via END(t-1))

        // ---- p2: stage A0(t+2); read R3 {bB <- fn4-7 kk1}; MFMA a1 x bA ----
        if (kt + 2 < NT) stageHalf(Ag(kt + 2, 0), As2);
#pragma unroll
        for (int fn = 0; fn < 4; ++fn) bB[fn] = *(const bf16x8*)(Bl + brow + (fn + 4) * 2048 + csw1);
        __builtin_amdgcn_s_setprio(1);
#pragma unroll
        for (int fm = 0; fm < 4; ++fm)
#pragma unroll
            for (int fn = 0; fn < 4; ++fn)
                acc[fm][fn] = __builtin_amdgcn_mfma_f32_16x16x32_bf16(a1[fm], bA[fn], acc[fm][fn], 0, 0, 0);
        __builtin_amdgcn_s_setprio(0);

        // ---- p3: stage A1(t+2); vmcnt(4); B3; read R0'(t+1); MFMA a1 x bB; END ----
        if (kt + 2 < NT) stageHalf(Ag(kt + 2, 1), As2 + 16384);
        if (kt + 1 < NT) {
            if (kt + 2 < NT) { asm volatile("s_waitcnt vmcnt(4)" ::: "memory"); }
            else             { asm volatile("s_waitcnt vmcnt(0)" ::: "memory"); }
            __builtin_amdgcn_sched_barrier(0);
            asm volatile("s_barrier" ::: "memory");          // B3: globalize vmcnt ->
                                                             // tile t+1 fully landed
            const char* nAl = (const char*)lds + anxt;
            const char* nBl = (const char*)lds + both;
#pragma unroll
            for (int fm = 0; fm < 4; ++fm) a0[fm] = *(const bf16x8*)(nAl + arow + fm * 2048 + csw0);
#pragma unroll
            for (int fn = 0; fn < 4; ++fn) bA[fn] = *(const bf16x8*)(nBl + brow + fn * 2048 + csw0);
        }
        __builtin_amdgcn_s_setprio(1);
#pragma unroll
        for (int fm = 0; fm < 4; ++fm)
#pragma unroll
            for (int fn = 0; fn < 4; ++fn)
                acc[fm][fn + 4] = __builtin_amdgcn_mfma_f32_16x16x32_bf16(a1[fm], bB[fn], acc[fm][fn + 4], 0, 0, 0);
        __builtin_amdgcn_s_setprio(0);
        asm volatile("s_barrier" ::: "memory");              // END: region handoff + swap

        const int at = acur; acur = anxt; anxt = ann; ann = at;
        const int bt = bcur; bcur = both; both = bt;
    }

    // epilogue: out = acc*scale + bias ; C/D layout col=lane&15, row=(lane>>4)*4+i
    const float scale = *wscale;
    const int orow0 = bm * 256 + wr * 64  + ((lane >> 4) << 2);
    const int ocol0 = bn * 256 + wc * 128 + (lane & 15);
#pragma unroll
    for (int fn = 0; fn < 8; ++fn) {
        const int col = ocol0 + 16 * fn;
        const float bb = bias[col];
#pragma unroll
        for (int fm = 0; fm < 4; ++fm) {
            const int row0 = orow0 + 16 * fm;
#pragma unroll
            for (int i = 0; i < 4; ++i)
                out[(size_t)(row0 + i) * N + col] = acc[fm][fn][i] * scale + bb;
        }
    }
}

// ---------- fallback: round-2 fused kernel (passes; used only if ws too small) ----------
__device__ __forceinline__ int swz(int row, int byte_in_row) {
    return row * 128 + (byte_in_row ^ ((row & 7) << 4));
}

__global__ __launch_bounds__(256) void qlinear_fused_kernel(
    const float* __restrict__ X, const int* __restrict__ W,
    const float* __restrict__ wscale, const float* __restrict__ bias,
    float* __restrict__ out, int M, int N, int K)
{
    __shared__ unsigned char smem[32768];

    const int t    = threadIdx.x;
    const int lane = t & 63;
    const int wid  = t >> 6;
    const int wr   = wid >> 1;
    const int wc   = wid & 1;

    const int ntn = N >> 7;
    const int bm  = blockIdx.x / ntn;
    const int bn  = blockIdx.x % ntn;
    const int NT  = K >> 6;

    const float* Ab = X + (size_t)bm * 128 * K;
    const int*   Bb = W + (size_t)bn * 128 * K;

    const int srow = t >> 4, sc4 = t & 15;

    f32x4 av[8];
    i32x4 bv[8];

    auto loadAB = [&](int kt) {
        const float* Ap = Ab + kt * 64 + sc4 * 4;
#pragma unroll
        for (int l = 0; l < 8; ++l)
            av[l] = *(const f32x4*)(Ap + (size_t)(srow + 16 * l) * K);
        const int* Bp = Bb + kt * 64 + sc4 * 4;
#pragma unroll
        for (int l = 0; l < 8; ++l)
            bv[l] = *(const i32x4*)(Bp + (size_t)(srow + 16 * l) * K);
    };

    auto writeAB = [&]() {
#pragma unroll
        for (int l = 0; l < 8; ++l) {
            const int row = srow + 16 * l;
            u32x2 pk;
            pk[0] = f2bf(av[l][0]) | (f2bf(av[l][1]) << 16);
            pk[1] = f2bf(av[l][2]) | (f2bf(av[l][3]) << 16);
            *(u32x2*)(smem + swz(row, sc4 * 8)) = pk;
        }
#pragma unroll
        for (int l = 0; l < 8; ++l) {
            const int row = srow + 16 * l;
            u32x2 pk;
            pk[0] = f2bf((float)bv[l][0]) | (f2bf((float)bv[l][1]) << 16);
            pk[1] = f2bf((float)bv[l][2]) | (f2bf((float)bv[l][3]) << 16);
            *(u32x2*)(smem + 16384 + swz(row, sc4 * 8)) = pk;
        }
    };

    f32x4 acc[4][4];
#pragma unroll
    for (int mi = 0; mi < 4; ++mi)
#pragma unroll
        for (int ni = 0; ni < 4; ++ni)
            acc[mi][ni] = (f32x4){0.f, 0.f, 0.f, 0.f};

    const int kbyte = (lane >> 4) * 16;
    const int afr   = wr * 64 + (lane & 15);
    const int bfr   = wc * 64 + (lane & 15);

    loadAB(0);

    for (int kt = 0; kt < NT; ++kt) {
        writeAB();
        __syncthreads();
        if (kt + 1 < NT) loadAB(kt + 1);
#pragma unroll
        for (int kk = 0; kk < 2; ++kk) {
            bf16x8 a[4], b[4];
#pragma unroll
            for (int mi = 0; mi < 4; ++mi)
                a[mi] = *(const bf16x8*)(smem + swz(afr + 16 * mi, kk * 64 + kbyte));
#pragma unroll
            for (int ni = 0; ni < 4; ++ni)
                b[ni] = *(const bf16x8*)(smem + 16384 + swz(bfr + 16 * ni, kk * 64 + kbyte));
#pragma unroll
            for (int mi = 0; mi < 4; ++mi)
#pragma unroll
                for (int ni = 0; ni < 4; ++ni)
                    acc[mi][ni] = __builtin_amdgcn_mfma_f32_16x16x32_bf16(
                        a[mi], b[ni], acc[mi][ni], 0, 0, 0);
        }
        __syncthreads();
    }

    const float scale = *wscale;
    const int orow0 = bm * 128 + wr * 64 + ((lane >> 4) << 2);
    const int ocol0 = bn * 128 + wc * 64 + (lane & 15);
#pragma unroll
    for (int ni = 0; ni < 4; ++ni) {
        const int col = ocol0 + 16 * ni;
        const float bb = bias[col];
#pragma unroll
        for (int mi = 0; mi < 4; ++mi) {
            const int row0 = orow0 + 16 * mi;
#pragma unroll
            for (int i = 0; i < 4; ++i)
                out[(size_t)(row0 + i) * N + col] = acc[mi][ni][i] * scale + bb;
        }
    }
}

extern "C" void kernel_launch(void* const* d_in, const int* in_sizes, int n_in,
                              void* d_out, int out_size, void* d_ws, size_t ws_size,
                              hipStream_t stream) {
    const float* x      = (const float*)d_in[0];
    const int*   w      = (const int*)d_in[1];      // int inputs arrive as int32
    const float* wscale = (const float*)d_in[2];
    const float* bias   = (const float*)d_in[3];
    float*       out    = (float*)d_out;

    const int DOUT = in_sizes[3];
    const int DIN  = in_sizes[1] / DOUT;
    const int M    = in_sizes[0] / DIN;

    const size_t xb_bytes = (size_t)M * DIN * 2;
    const size_t wb_bytes = (size_t)DOUT * DIN * 2;

    if (ws_size >= xb_bytes + wb_bytes && (M % 256) == 0 && (DOUT % 256) == 0
        && (DIN % 64) == 0 && (DIN / 64) >= 2) {
        unsigned short* xb = (unsigned short*)d_ws;
        unsigned short* wb = (unsigned short*)((char*)d_ws + xb_bytes);

        const long long nx8 = (long long)M * DIN / 8;
        const long long nw8 = (long long)DOUT * DIN / 8;
        convert_xw_kernel<<<2048, 256, 0, stream>>>(x, w, xb, wb, nx8, nx8 + nw8);

        dim3 grid((M / 256) * (DOUT / 256));
        gemm256_kernel<<<grid, 512, 0, stream>>>(xb, wb, wscale, bias, out, M, DOUT, DIN);
    } else {
        dim3 grid((M / 128) * (DOUT / 128));
        qlinear_fused_kernel<<<grid, 256, 0, stream>>>(x, w, wscale, bias, out, M, DOUT, DIN);
    }
}